// Round 1
// baseline (66.777 us; speedup 1.0000x reference)
//
#include <hip/hip_runtime.h>
#include <cstdint>
#include <climits>

#define GRID_N 16777216
#define N_STEPS 100

// nan_to_num(psi, nan=0.0, posinf=1.0, neginf=-1.0)
__device__ __forceinline__ float fixv(float v) {
    if (isnan(v)) return 0.0f;
    if (isinf(v)) return v > 0.0f ? 1.0f : -1.0f;
    return v;
}

// psi0*psi0 + psi1*psi1 in strict f32, no FMA contraction (match host semantics)
__device__ __forceinline__ float raw_prob(float a, float b) {
    return __fadd_rn(__fmul_rn(a, a), __fmul_rn(b, b));
}

__global__ __launch_bounds__(256) void qpe_sum_kernel(const float4* __restrict__ psi4,
                                                      double* __restrict__ partials,
                                                      int n4) {
    double acc = 0.0;
    int stride = gridDim.x * blockDim.x;
    for (int i = blockIdx.x * blockDim.x + threadIdx.x; i < n4; i += stride) {
        float4 v = psi4[i];
        float a0 = fixv(v.x), b0 = fixv(v.y);
        float a1 = fixv(v.z), b1 = fixv(v.w);
        acc += (double)raw_prob(a0, b0);
        acc += (double)raw_prob(a1, b1);
    }
    __shared__ double sm[256];
    sm[threadIdx.x] = acc;
    __syncthreads();
    // fixed-order tree reduce -> deterministic
    for (int s = 128; s > 0; s >>= 1) {
        if (threadIdx.x < s) sm[threadIdx.x] += sm[threadIdx.x + s];
        __syncthreads();
    }
    if (threadIdx.x == 0) partials[blockIdx.x] = sm[0];
}

__global__ void qpe_walk_kernel(const float* __restrict__ psi,
                                const float* __restrict__ noise,
                                const float* __restrict__ x,
                                const int* __restrict__ c0p,
                                const double* __restrict__ partials, int nparts,
                                float* __restrict__ out) {
    int lane = threadIdx.x;
    // deterministic f64 reduce of per-block partials (fixed order)
    double acc = 0.0;
    for (int i = lane; i < nparts; i += 64) acc += partials[i];
    for (int off = 32; off > 0; off >>= 1) acc += __shfl_down(acc, off, 64);
    if (lane != 0) return;

    float S = (float)acc;  // best estimate of ref's f32 sum (exactly-rounded)
    const float DXf    = (float)(20.0 / (double)(GRID_N - 1));
    const float TWODXf = (float)(2.0 * (20.0 / (double)(GRID_N - 1)));
    const float DTf    = 0.01f;
    const float SQ2DTf = (float)0.14142135623730950488;  // np.sqrt(0.02) -> f32
    float norm = __fadd_rn(__fmul_rn(S, DXf), 1e-8f);

    int c = *c0p;
    for (int t = 0; t < N_STEPS; ++t) {
        float s;
        if (c <= 0 || c >= GRID_N - 1) {
            s = 0.0f;  // ref zeroes score at boundaries
        } else {
            float a1 = fixv(psi[2 * (c + 1)]);
            float b1 = fixv(psi[2 * (c + 1) + 1]);
            float a0 = fixv(psi[2 * (c - 1)]);
            float b0 = fixv(psi[2 * (c - 1) + 1]);
            float p1 = fmaxf(__fdiv_rn(raw_prob(a1, b1), norm), 1e-12f);
            float p0 = fmaxf(__fdiv_rn(raw_prob(a0, b0), norm), 1e-12f);
            float lp1 = logf(p1);
            float lp0 = logf(p0);
            s = __fdiv_rn(__fsub_rn(lp1, lp0), TWODXf);
            // ref applies nan_to_num(score); s is always finite here (lp bounded)
        }
        float n = noise[t];
        float move = __fadd_rn(__fmul_rn(s, DTf), __fmul_rn(n, SQ2DTf));
        if (!isfinite(move)) move = 0.0f;
        float sf = __fdiv_rn(move, DXf);
        int shift;
        // x86 cvttss2si semantics: out-of-range or NaN -> INT_MIN (NOT saturate)
        if (!(sf >= -2147483648.0f && sf < 2147483648.0f)) shift = INT_MIN;
        else shift = (int)sf;  // in-range: truncation toward zero, matches host
        // int32 wrapping add (XLA/NumPy wrap), then clip
        c = (int)((unsigned)c + (unsigned)shift);
        if (c < 0) c = 0;
        if (c > GRID_N - 1) c = GRID_N - 1;
    }
    out[0] = x[c];
}

extern "C" void kernel_launch(void* const* d_in, const int* in_sizes, int n_in,
                              void* d_out, int out_size, void* d_ws, size_t ws_size,
                              hipStream_t stream) {
    const float* psi   = (const float*)d_in[0];
    const float* noise = (const float*)d_in[1];
    const float* x     = (const float*)d_in[2];
    const int*   c0    = (const int*)d_in[3];
    float* out = (float*)d_out;

    double* partials = (double*)d_ws;
    int nblocks = 1024;
    size_t maxp = ws_size / sizeof(double);
    if ((size_t)nblocks > maxp && maxp > 0) nblocks = (int)maxp;
    if (nblocks < 1) nblocks = 1;

    qpe_sum_kernel<<<nblocks, 256, 0, stream>>>((const float4*)psi, partials, GRID_N / 2);
    qpe_walk_kernel<<<1, 64, 0, stream>>>(psi, noise, x, c0, partials, nblocks, out);
}

// Round 2
// 63.920 us; speedup vs baseline: 1.0447x; 1.0447x over previous
//
#include <hip/hip_runtime.h>
#include <cstdint>
#include <climits>

#define GRID_N 16777216
#define N_STEPS 100

// nan_to_num(psi, nan=0.0, posinf=1.0, neginf=-1.0)
__device__ __forceinline__ float fixv(float v) {
    if (isnan(v)) return 0.0f;
    if (isinf(v)) return v > 0.0f ? 1.0f : -1.0f;
    return v;
}

// psi0*psi0 + psi1*psi1 in strict f32, no FMA contraction (match host semantics)
__device__ __forceinline__ float raw_prob(float a, float b) {
    return __fadd_rn(__fmul_rn(a, a), __fmul_rn(b, b));
}

__global__ __launch_bounds__(256) void qpe_sum_kernel(const float4* __restrict__ psi4,
                                                      double* __restrict__ partials,
                                                      int n4) {
    double acc = 0.0;
    int stride = gridDim.x * blockDim.x;
    for (int i = blockIdx.x * blockDim.x + threadIdx.x; i < n4; i += stride) {
        float4 v = psi4[i];
        float a0 = fixv(v.x), b0 = fixv(v.y);
        float a1 = fixv(v.z), b1 = fixv(v.w);
        acc += (double)raw_prob(a0, b0);
        acc += (double)raw_prob(a1, b1);
    }
    __shared__ double sm[256];
    sm[threadIdx.x] = acc;
    __syncthreads();
    // fixed-order tree reduce -> deterministic
    for (int s = 128; s > 0; s >>= 1) {
        if (threadIdx.x < s) sm[threadIdx.x] += sm[threadIdx.x + s];
        __syncthreads();
    }
    if (threadIdx.x == 0) partials[blockIdx.x] = sm[0];
}

__global__ void qpe_walk_kernel(const float* __restrict__ psi,
                                const float* __restrict__ noise,
                                const float* __restrict__ x,
                                const int* __restrict__ c0p,
                                const double* __restrict__ partials, int nparts,
                                float* __restrict__ out) {
    int lane = threadIdx.x;
    const float DXf    = (float)(20.0 / (double)(GRID_N - 1));
    const float TWODXf = (float)(2.0 * (20.0 / (double)(GRID_N - 1)));
    const float DTf    = 0.01f;
    const float SQ2DTf = (float)0.14142135623730950488;  // np.sqrt(0.02) -> f32

    // ---- phase 0: parallel prefetch of candidate positions ----
    // From a boundary (score==0) the next index depends ONLY on noise[t]:
    //   cand = clip(b + int(noise[t]*sqrt(2dt)/DX)),  b in {0, GRID-1}.
    // Touch psi[2*(cand-1)] and psi[2*(cand+1)+1] to warm the (<=2) cache
    // lines each interior step will need. Purely a cache hint; walk loads
    // below are still authoritative.
    float keep = 0.0f;
    for (int i = lane; i < 2 * N_STEPS + 1; i += 64) {
        int c;
        if (i == 2 * N_STEPS) {
            c = *c0p;
        } else {
            int t = i >> 1;
            float n = noise[t];
            float move = __fmul_rn(n, SQ2DTf);   // score==0 at boundary
            float sf = __fdiv_rn(move, DXf);
            int shift;
            if (!(sf >= -2147483648.0f && sf < 2147483648.0f)) shift = INT_MIN;
            else shift = (int)sf;
            int b = (i & 1) ? (GRID_N - 1) : 0;
            c = (int)((unsigned)b + (unsigned)shift);
            if (c < 0) c = 0;
            if (c > GRID_N - 1) c = GRID_N - 1;
        }
        if (c > 0 && c < GRID_N - 1) {
            keep += psi[2 * (c - 1)] + psi[2 * (c + 1) + 1];
        }
    }
    asm volatile("" :: "v"(keep));  // keep prefetch loads live, no side effect

    // ---- phase 1: deterministic f64 reduce of per-block partials ----
    double acc = 0.0;
    for (int i = lane; i < nparts; i += 64) acc += partials[i];
    for (int off = 32; off > 0; off >>= 1) acc += __shfl_down(acc, off, 64);
    if (lane != 0) return;

    float S = (float)acc;  // ref's f32 sum (exactly-rounded from f64)
    float norm = __fadd_rn(__fmul_rn(S, DXf), 1e-8f);

    // ---- phase 2: sequential Langevin walk (lane 0) ----
    int c = *c0p;
    for (int t = 0; t < N_STEPS; ++t) {
        float s;
        if (c <= 0 || c >= GRID_N - 1) {
            s = 0.0f;  // ref zeroes score at boundaries
        } else {
            float a1 = fixv(psi[2 * (c + 1)]);
            float b1 = fixv(psi[2 * (c + 1) + 1]);
            float a0 = fixv(psi[2 * (c - 1)]);
            float b0 = fixv(psi[2 * (c - 1) + 1]);
            float p1 = fmaxf(__fdiv_rn(raw_prob(a1, b1), norm), 1e-12f);
            float p0 = fmaxf(__fdiv_rn(raw_prob(a0, b0), norm), 1e-12f);
            float lp1 = logf(p1);
            float lp0 = logf(p0);
            s = __fdiv_rn(__fsub_rn(lp1, lp0), TWODXf);
        }
        float n = noise[t];
        float move = __fadd_rn(__fmul_rn(s, DTf), __fmul_rn(n, SQ2DTf));
        if (!isfinite(move)) move = 0.0f;
        float sf = __fdiv_rn(move, DXf);
        int shift;
        // x86 cvttss2si semantics: out-of-range or NaN -> INT_MIN (NOT saturate)
        if (!(sf >= -2147483648.0f && sf < 2147483648.0f)) shift = INT_MIN;
        else shift = (int)sf;  // in-range: truncation toward zero, matches host
        // int32 wrapping add (XLA/NumPy wrap), then clip
        c = (int)((unsigned)c + (unsigned)shift);
        if (c < 0) c = 0;
        if (c > GRID_N - 1) c = GRID_N - 1;
    }
    out[0] = x[c];
}

extern "C" void kernel_launch(void* const* d_in, const int* in_sizes, int n_in,
                              void* d_out, int out_size, void* d_ws, size_t ws_size,
                              hipStream_t stream) {
    const float* psi   = (const float*)d_in[0];
    const float* noise = (const float*)d_in[1];
    const float* x     = (const float*)d_in[2];
    const int*   c0    = (const int*)d_in[3];
    float* out = (float*)d_out;

    double* partials = (double*)d_ws;
    int nblocks = 2048;
    size_t maxp = ws_size / sizeof(double);
    if ((size_t)nblocks > maxp && maxp > 0) nblocks = (int)maxp;
    if (nblocks < 1) nblocks = 1;

    qpe_sum_kernel<<<nblocks, 256, 0, stream>>>((const float4*)psi, partials, GRID_N / 2);
    qpe_walk_kernel<<<1, 64, 0, stream>>>(psi, noise, x, c0, partials, nblocks, out);
}

// Round 3
// 45.841 us; speedup vs baseline: 1.4567x; 1.3944x over previous
//
#include <hip/hip_runtime.h>
#include <cstdint>
#include <climits>

#define GRID_N 16777216
#define N_STEPS 100
#define NCAND (2 * N_STEPS + 1)   // 200 boundary-origin candidates + c0

// nan_to_num(psi, nan=0.0, posinf=1.0, neginf=-1.0)
__device__ __forceinline__ float fixv(float v) {
    if (isnan(v)) return 0.0f;
    if (isinf(v)) return v > 0.0f ? 1.0f : -1.0f;
    return v;
}

// psi0*psi0 + psi1*psi1 in strict f32, no FMA contraction (match host semantics)
__device__ __forceinline__ float raw_prob(float a, float b) {
    return __fadd_rn(__fmul_rn(a, a), __fmul_rn(b, b));
}

// x86 cvttss2si semantics: out-of-range or NaN -> INT_MIN (NOT GPU saturation)
__device__ __forceinline__ int host_f2i(float sf) {
    if (!(sf >= -2147483648.0f && sf < 2147483648.0f)) return INT_MIN;
    return (int)sf;
}

__device__ __forceinline__ int wrap_clip(int c, int shift) {
    int r = (int)((unsigned)c + (unsigned)shift);  // int32 wrapping add (XLA/NumPy)
    if (r < 0) r = 0;
    if (r > GRID_N - 1) r = GRID_N - 1;
    return r;
}

__global__ __launch_bounds__(256) void qpe_sum_kernel(const float4* __restrict__ psi4,
                                                      double* __restrict__ partials,
                                                      int n4) {
    double acc = 0.0;
    int stride = gridDim.x * blockDim.x;
    for (int i = blockIdx.x * blockDim.x + threadIdx.x; i < n4; i += stride) {
        float4 v = psi4[i];
        float a0 = fixv(v.x), b0 = fixv(v.y);
        float a1 = fixv(v.z), b1 = fixv(v.w);
        acc += (double)raw_prob(a0, b0);
        acc += (double)raw_prob(a1, b1);
    }
    __shared__ double sm[256];
    sm[threadIdx.x] = acc;
    __syncthreads();
    for (int s = 128; s > 0; s >>= 1) {   // fixed-order tree -> deterministic
        if (threadIdx.x < s) sm[threadIdx.x] += sm[threadIdx.x + s];
        __syncthreads();
    }
    if (threadIdx.x == 0) partials[blockIdx.x] = sm[0];
}

__global__ __launch_bounds__(256) void qpe_walk_kernel(const float* __restrict__ psi,
                                                       const float* __restrict__ noise,
                                                       const float* __restrict__ x,
                                                       const int* __restrict__ c0p,
                                                       const double* __restrict__ partials,
                                                       int nparts,
                                                       float* __restrict__ out) {
    const int tid = threadIdx.x;
    const float DXf    = (float)(20.0 / (double)(GRID_N - 1));
    const float TWODXf = (float)(2.0 * (20.0 / (double)(GRID_N - 1)));
    const float DTf    = 0.01f;
    const float SQ2DTf = (float)0.14142135623730950488;  // np.sqrt(0.02) -> f32

    __shared__ int    cand_c[256];
    __shared__ float  cand_s[256];
    __shared__ double red[256];
    __shared__ float  norm_sh;

    // ---- phase A: candidate positions; issue their psi loads now ----
    // From a boundary b at step t (score==0 there), the next index is
    //   clip(wrap(b, int((noise[t]*sqrt2dt)/DX)))  -- a function of noise only.
    // tid = 2t + parity (parity 1 -> b = GRID-1); tid 200 -> c0 itself.
    int myc = -1;
    float2 lo = make_float2(0.0f, 0.0f), hi = make_float2(0.0f, 0.0f);
    if (tid < NCAND) {
        if (tid == NCAND - 1) {
            myc = *c0p;
        } else {
            int t = tid >> 1;
            float n = noise[t];
            // identical fp sequence to a walk step with s==0:
            float move = __fadd_rn(__fmul_rn(0.0f, DTf), __fmul_rn(n, SQ2DTf));
            if (!isfinite(move)) move = 0.0f;
            int shift = host_f2i(__fdiv_rn(move, DXf));
            int b = (tid & 1) ? (GRID_N - 1) : 0;
            myc = wrap_clip(b, shift);
        }
        if (myc > 0 && myc < GRID_N - 1) {
            lo = *(const float2*)(psi + 2 * myc - 2);  // psi[c-1][0..1]
            hi = *(const float2*)(psi + 2 * myc + 2);  // psi[c+1][0..1]
        }
    }

    // ---- phase B: deterministic f64 reduce of per-block partials ----
    double acc = 0.0;
    for (int i = tid; i < nparts; i += 256) acc += partials[i];
    red[tid] = acc;
    __syncthreads();
    for (int s = 128; s > 0; s >>= 1) {
        if (tid < s) red[tid] += red[tid + s];
        __syncthreads();
    }
    if (tid == 0) {
        float S = (float)red[0];
        norm_sh = __fadd_rn(__fmul_rn(S, DXf), 1e-8f);
    }
    __syncthreads();
    float norm = norm_sh;

    // ---- phase C: per-candidate score -> LDS table (exact ref fp sequence) ----
    float s_val = 0.0f;
    if (tid < NCAND && myc > 0 && myc < GRID_N - 1) {
        float a0 = fixv(lo.x), b0 = fixv(lo.y);
        float a1 = fixv(hi.x), b1 = fixv(hi.y);
        float p1 = fmaxf(__fdiv_rn(raw_prob(a1, b1), norm), 1e-12f);
        float p0 = fmaxf(__fdiv_rn(raw_prob(a0, b0), norm), 1e-12f);
        s_val = __fdiv_rn(__fsub_rn(logf(p1), logf(p0)), TWODXf);
    }
    cand_c[tid] = (tid < NCAND) ? myc : -1;
    cand_s[tid] = s_val;
    __syncthreads();

    if (tid != 0) return;

    // ---- phase D: sequential walk, LDS table lookups ----
    int c = cand_c[NCAND - 1];   // == *c0p
    int pred = NCAND - 1;        // candidate index describing current c (-1 = unknown)
    for (int t = 0; t < N_STEPS; ++t) {
        float s;
        bool at_boundary = (c <= 0 || c >= GRID_N - 1);
        if (at_boundary) {
            s = 0.0f;
        } else if (pred >= 0 && cand_c[pred] == c) {
            s = cand_s[pred];
        } else {
            // rare fallback: position not in candidate table -> compute from global
            float a1 = fixv(psi[2 * (c + 1)]);
            float b1 = fixv(psi[2 * (c + 1) + 1]);
            float a0 = fixv(psi[2 * (c - 1)]);
            float b0 = fixv(psi[2 * (c - 1) + 1]);
            float p1 = fmaxf(__fdiv_rn(raw_prob(a1, b1), norm), 1e-12f);
            float p0 = fmaxf(__fdiv_rn(raw_prob(a0, b0), norm), 1e-12f);
            s = __fdiv_rn(__fsub_rn(logf(p1), logf(p0)), TWODXf);
        }
        float n = noise[t];
        float move = __fadd_rn(__fmul_rn(s, DTf), __fmul_rn(n, SQ2DTf));
        if (!isfinite(move)) move = 0.0f;
        int shift = host_f2i(__fdiv_rn(move, DXf));
        // next position's candidate identity: from boundary at step t it is
        // exactly cand[2t+parity] (bit-identical arithmetic above)
        pred = at_boundary ? (2 * t + ((c != 0) ? 1 : 0)) : -1;
        c = wrap_clip(c, shift);
    }
    out[0] = x[c];
}

extern "C" void kernel_launch(void* const* d_in, const int* in_sizes, int n_in,
                              void* d_out, int out_size, void* d_ws, size_t ws_size,
                              hipStream_t stream) {
    const float* psi   = (const float*)d_in[0];
    const float* noise = (const float*)d_in[1];
    const float* x     = (const float*)d_in[2];
    const int*   c0    = (const int*)d_in[3];
    float* out = (float*)d_out;

    double* partials = (double*)d_ws;
    int nblocks = 2048;
    size_t maxp = ws_size / sizeof(double);
    if ((size_t)nblocks > maxp && maxp > 0) nblocks = (int)maxp;
    if (nblocks < 1) nblocks = 1;

    qpe_sum_kernel<<<nblocks, 256, 0, stream>>>((const float4*)psi, partials, GRID_N / 2);
    qpe_walk_kernel<<<1, 256, 0, stream>>>(psi, noise, x, c0, partials, nblocks, out);
}